// Round 16
// baseline (689.065 us; speedup 1.0000x reference)
//
#include <hip/hip_runtime.h>
#include <hip/hip_bf16.h>
#include <stdint.h>
#include <stddef.h>

#define NH 12
#define DKH 64
#define DM 768
#define SS 4096

typedef __attribute__((ext_vector_type(8))) short bf16x8;
typedef __attribute__((ext_vector_type(4))) float f32x4;
typedef __attribute__((ext_vector_type(16))) float f32x16;

__device__ __forceinline__ unsigned short f2bf(float x) {
  union { float f; unsigned int u; } a; a.f = x;
  unsigned int r = a.u + 0x7fffu + ((a.u >> 16) & 1u);
  return (unsigned short)(r >> 16);
}

__device__ __forceinline__ unsigned pkbf2(float a, float b) {
  union { __hip_bfloat162 h; unsigned u; } x;
  x.h = __float22bfloat162_rn(float2{a, b});
  return x.u;
}

__device__ __forceinline__ unsigned cvt_pk_bf16(float lo, float hi) {
  unsigned r;
  asm("v_cvt_pk_bf16_f32 %0, %1, %2" : "=v"(r) : "v"(lo), "v"(hi));
  return r;
}

__device__ __forceinline__ void plane32_swap(unsigned& a, unsigned& b) {
  asm("v_permlane32_swap_b32 %0, %1" : "+v"(a), "+v"(b));
}

__device__ __forceinline__ float fast_exp2(float x) {
#if __has_builtin(__builtin_amdgcn_exp2f)
  return __builtin_amdgcn_exp2f(x);
#else
  return exp2f(x);
#endif
}

// combine two bf16x2 words from the two KV-split partials, scale by inv
__device__ __forceinline__ unsigned comb2(unsigned pa, unsigned pb, float inv) {
  union { unsigned v; float f; } lo0, hi0, lo1, hi1;
  lo0.v = (pa & 0xffffu) << 16; hi0.v = pa & 0xffff0000u;
  lo1.v = (pb & 0xffffu) << 16; hi1.v = pb & 0xffff0000u;
  return pkbf2((lo0.f + lo1.f) * inv, (hi0.f + hi1.f) * inv);
}

// global -> LDS async 16B/lane. LDS dest is wave-uniform base + lane*16.
__device__ __forceinline__ void gload16(const void* g, void* l) {
  __builtin_amdgcn_global_load_lds(
      (const __attribute__((address_space(1))) void*)g,
      (__attribute__((address_space(3))) void*)l, 16, 0, 0);
}

// ---------------------------------------------------------------------------
// Prep kernel: qkv fp32->bf16 (blocks 0..9215) + weight repack (9216..11519).
// wq gets Q-scale 0.125*log2e folded in.
// ---------------------------------------------------------------------------
__global__ __launch_bounds__(256) void prep(
    const float* __restrict__ Q, const float* __restrict__ K,
    const float* __restrict__ V, const float* __restrict__ WQ,
    const float* __restrict__ WK, const float* __restrict__ WV,
    const float* __restrict__ WO, unsigned short* __restrict__ qkv,
    unsigned short* __restrict__ wq, unsigned short* __restrict__ wk,
    unsigned short* __restrict__ wv, unsigned short* __restrict__ wo) {
  int bx = blockIdx.x;
  if (bx < 9216) {
    int gid = bx * 256 + threadIdx.x;
    int t = gid / 786432, e = gid % 786432;
    const float* src = (t == 0) ? Q : (t == 1) ? K : V;
    float4 a = *(const float4*)(src + (size_t)e * 8);
    float4 c = *(const float4*)(src + (size_t)e * 8 + 4);
    union { unsigned u[4]; uint4 v; } o;
    o.u[0] = pkbf2(a.x, a.y); o.u[1] = pkbf2(a.z, a.w);
    o.u[2] = pkbf2(c.x, c.y); o.u[3] = pkbf2(c.z, c.w);
    *(uint4*)(qkv + (size_t)t * 6291456 + (size_t)e * 8) = o.v;
  } else {
    int idx = (bx - 9216) * 256 + threadIdx.x;
    if (idx >= DM * DM) return;
    int n = idx / DM, k = idx % DM;
    int src = ((n >> 6) * DM + k) * DKH + (n & 63);
    wq[idx] = f2bf(WQ[src] * 0.18033688011112042f);
    wk[idx] = f2bf(WK[src]);
    wv[idx] = f2bf(WV[src]);
    wo[idx] = f2bf(WO[k * DM + n]);
  }
}

// ---------------------------------------------------------------------------
// Merged projection GEMM (r15 version: uniform swapped MFMA, vectorized
// epilogue stores). Unchanged.
// ---------------------------------------------------------------------------
__global__ __launch_bounds__(256, 2) void proj_gemm3(
    const unsigned short* __restrict__ Abase,
    const unsigned short* __restrict__ Wbase,
    unsigned short* __restrict__ Obase) {
  __shared__ unsigned short As[2][128 * 64];
  __shared__ unsigned short Bs[2][96 * 64];
  const int tid = threadIdx.x;
  const int lane = tid & 63, wave = tid >> 6;
  const int wm = wave >> 1, wn = wave & 1;
  const int l15 = lane & 15, lhi = lane >> 4;
  const int lrow = lane >> 3;
  const int schunk = (lane & 7) ^ lrow;

  int fid = blockIdx.x + (blockIdx.y << 3) + (blockIdx.z << 9);
  int nid = (fid & 7) * 192 + (fid >> 3);
  const int bx = nid & 7;
  const int rem = nid >> 3;
  const int by = rem & 63, z = rem >> 6;
  const bool z2 = (z == 2);

  const unsigned short* A = Abase + (size_t)z * 6291456;
  const unsigned short* Wt = Wbase + (size_t)z * DM * DM;
  unsigned short* out = Obase + (size_t)z * 2 * NH * SS * DKH;
  const int m0 = by * 128, n0 = bx * 96;

  auto stage = [&](int k0, int buf) {
#pragma unroll
    for (int i = 0; i < 4; ++i) {
      int r = wave * 32 + i * 8;
      gload16(A + (size_t)(m0 + r + lrow) * DM + k0 + schunk * 8, &As[buf][r * 64]);
    }
#pragma unroll
    for (int i = 0; i < 3; ++i) {
      int r = wave * 24 + i * 8;
      gload16(Wt + (size_t)(n0 + r + lrow) * DM + k0 + schunk * 8, &Bs[buf][r * 64]);
    }
  };

  f32x4 acc[4][3] = {};

  stage(0, 0);
  stage(64, 1);

  for (int t = 0; t < 12; ++t) {
    if (t < 11) asm volatile("s_waitcnt vmcnt(7)" ::: "memory");
    else        asm volatile("s_waitcnt vmcnt(0)" ::: "memory");
    asm volatile("s_barrier" ::: "memory");
    const int buf = t & 1;
    bf16x8 af[4][2], bfr[3][2];
#pragma unroll
    for (int m = 0; m < 4; ++m) {
      int row = wm * 64 + m * 16 + l15;
#pragma unroll
      for (int ks = 0; ks < 2; ++ks)
        af[m][ks] = *(const bf16x8*)&As[buf][row * 64 + (((ks * 4 + lhi) ^ (row & 7)) * 8)];
    }
#pragma unroll
    for (int n = 0; n < 3; ++n) {
      int row = wn * 48 + n * 16 + l15;
#pragma unroll
      for (int ks = 0; ks < 2; ++ks)
        bfr[n][ks] = *(const bf16x8*)&Bs[buf][row * 64 + (((ks * 4 + lhi) ^ (row & 7)) * 8)];
    }
    asm volatile("s_waitcnt lgkmcnt(0)" ::: "memory");
    asm volatile("s_barrier" ::: "memory");
    if (t + 2 < 12) stage((t + 2) * 64, buf);
    __builtin_amdgcn_s_setprio(1);
#pragma unroll
    for (int ks = 0; ks < 2; ++ks)
#pragma unroll
      for (int m = 0; m < 4; ++m)
#pragma unroll
        for (int n = 0; n < 3; ++n)
          acc[m][n] = __builtin_amdgcn_mfma_f32_16x16x32_bf16(bfr[n][ks], af[m][ks], acc[m][n], 0, 0, 0);
    __builtin_amdgcn_s_setprio(0);
  }

  if (!z2) {
#pragma unroll
    for (int m = 0; m < 4; ++m) {
      int srow = m0 + wm * 64 + m * 16 + l15;
      int bb = srow >> 12, s = srow & 4095;
#pragma unroll
      for (int n = 0; n < 3; ++n) {
        int colb = n0 + wn * 48 + n * 16 + lhi * 4;
        int hh = colb >> 6, dk = colb & 63;
        union { unsigned short u[4]; uint2 v; } p;
#pragma unroll
        for (int r = 0; r < 4; ++r) p.u[r] = f2bf(acc[m][n][r]);
        *(uint2*)&out[((size_t)(bb * NH + hh) * SS + s) * DKH + dk] = p.v;
      }
    }
  } else {
#pragma unroll
    for (int m = 0; m < 4; ++m) {
      int srow = m0 + wm * 64 + m * 16 + l15;
      int bb = srow >> 12, s = srow & 4095;
#pragma unroll
      for (int n = 0; n < 3; ++n) {
#pragma unroll
        for (int r = 0; r < 4; ++r) {
          int col = n0 + wn * 48 + n * 16 + lhi * 4 + r;
          int hh = col >> 6, dk = col & 63;
          out[((size_t)(bb * NH + hh) * DKH + dk) * SS + s] = f2bf(acc[m][n][r]);
        }
      }
    }
  }
}

// ---------------------------------------------------------------------------
// pack 32 f32 P-values into 4 PV B-fragments (proven mapping)
// ---------------------------------------------------------------------------
__device__ __forceinline__ void pack_pb(const f32x16& s0, const f32x16& s1, bf16x8* pb) {
#pragma unroll
  for (int h2 = 0; h2 < 2; ++h2) {
    unsigned c0a = cvt_pk_bf16(s0[8 * h2 + 0], s0[8 * h2 + 1]);
    unsigned c1a = cvt_pk_bf16(s0[8 * h2 + 2], s0[8 * h2 + 3]);
    unsigned c0b = cvt_pk_bf16(s0[8 * h2 + 4], s0[8 * h2 + 5]);
    unsigned c1b = cvt_pk_bf16(s0[8 * h2 + 6], s0[8 * h2 + 7]);
    plane32_swap(c0a, c0b);
    plane32_swap(c1a, c1b);
    union { unsigned u[4]; bf16x8 v; } f;
    f.u[0] = c0a; f.u[1] = c1a; f.u[2] = c0b; f.u[3] = c1b;
    pb[h2] = f.v;
  }
#pragma unroll
  for (int h2 = 0; h2 < 2; ++h2) {
    unsigned c0a = cvt_pk_bf16(s1[8 * h2 + 0], s1[8 * h2 + 1]);
    unsigned c1a = cvt_pk_bf16(s1[8 * h2 + 2], s1[8 * h2 + 3]);
    unsigned c0b = cvt_pk_bf16(s1[8 * h2 + 4], s1[8 * h2 + 5]);
    unsigned c1b = cvt_pk_bf16(s1[8 * h2 + 6], s1[8 * h2 + 7]);
    plane32_swap(c0a, c0b);
    plane32_swap(c1a, c1b);
    union { unsigned u[4]; bf16x8 v; } f;
    f.u[0] = c0a; f.u[1] = c1a; f.u[2] = c0b; f.u[3] = c1b;
    pb[2 + h2] = f.v;
  }
}

__device__ __forceinline__ float tree16(const f32x16& v) {
  float a = (v[0] + v[1]) + (v[2] + v[3]);
  float b = (v[4] + v[5]) + (v[6] + v[7]);
  float c = (v[8] + v[9]) + (v[10] + v[11]);
  float d = (v[12] + v[13]) + (v[14] + v[15]);
  return (a + b) + (c + d);
}

// ---------------------------------------------------------------------------
// Flash attention v16: r12 body with 24 KB LDS -> residency 6 (one uniform
// round, 24 waves/CU). K double-buffered (2x8KB), V single-buffered (8KB,
// r5/r10-proven sync): per iter {stageK(t+1); vmcnt(4); bar} QK
// {exp/pack} {vmcnt(2); bar} PV {lgkm0; bar; stageV(t+1)}. Pre-loop
// vmcnt(0)+bar makes loop-FIFO counts exact (only staged loads outstanding).
// Split-KV x2 across blocks, bf16 partials, grid (32,24,2)=1536 = 6/CU.
// ---------------------------------------------------------------------------
__global__ __launch_bounds__(256, 6) void flash_attn(
    const unsigned short* __restrict__ Qp, const unsigned short* __restrict__ Kp,
    const unsigned short* __restrict__ Vt, unsigned short* __restrict__ Opart,
    float* __restrict__ Lpart) {
  __shared__ unsigned short Kb[2][4096];  // K dbuf, 8 KB each
  __shared__ unsigned short Vb[4096];     // V single buf, 8 KB
  const int tid = threadIdx.x;
  const int lane = tid & 63, wave = tid >> 6;
  const int ql = lane & 31, hi = lane >> 5;

  int fid = blockIdx.x + (blockIdx.y << 5) + (blockIdx.z << 9) + (blockIdx.z << 8);
  int nid = (fid & 7) * 192 + (fid >> 3);
  const int qb = nid & 31;
  const int rem = nid >> 5;
  const int bh = rem % 24, split = rem / 24;
  const int q0w = qb * 128 + wave * 32;
  const int kvbase = split * (SS / 2);

  bf16x8 qf[4];
  {
    const unsigned short* qp = Qp + ((size_t)bh * SS + q0w + ql) * DKH;
#pragma unroll
    for (int s = 0; s < 4; ++s)
      qf[s] = *(const bf16x8*)(qp + s * 16 + hi * 8);
  }

  const unsigned short* gK = Kp + (size_t)bh * SS * DKH;
  const unsigned short* gV = Vt + (size_t)bh * DKH * SS;
  const int lrow = lane >> 3;
  const int sch = ((lane & 7) ^ lrow) * 8;
  const int xs = (ql & 7) << 3;

  auto stageK = [&](int kv0, int buf) {
#pragma unroll
    for (int i = 0; i < 2; ++i) {
      int r = wave * 16 + i * 8;
      gload16(gK + (size_t)(kv0 + r + lrow) * DKH + sch, &Kb[buf][r * 64]);
    }
  };
  auto stageV = [&](int kv0) {
#pragma unroll
    for (int i = 0; i < 2; ++i) {
      int r = wave * 16 + i * 8;
      gload16(gV + (size_t)(r + lrow) * SS + kv0 + sch, &Vb[r * 64]);
    }
  };

  stageK(kvbase, 0);
  stageV(kvbase);
  // drain everything (incl. qf register loads) so loop FIFO counts are exact
  asm volatile("s_waitcnt vmcnt(0)" ::: "memory");
  __builtin_amdgcn_s_barrier();

  f32x16 oA = {}, oB = {};
  float lp = 0.f;
  const f32x16 zc = {};

  for (int it = 0; it < 32; ++it) {
    const int buf = it & 1;
    const bool nl = (it + 1 < 32);
    // per-wave FIFO at entry: V(it)[2] then K(it+1) staged below
    if (nl) {
      stageK(kvbase + (it + 1) * 64, buf ^ 1);
      asm volatile("s_waitcnt vmcnt(4)" ::: "memory");  // K(it) landed (it>0: noop-ish)
    }
    __builtin_amdgcn_s_barrier();  // all waves' K(it) visible
    __builtin_amdgcn_sched_barrier(0);
    const unsigned short* Ks = &Kb[buf][0];

    f32x16 s0, s1;
    __builtin_amdgcn_s_setprio(1);
    {
      bf16x8 ka0 = *(const bf16x8*)&Ks[ql * 64 + ((hi * 8) ^ xs)];
      bf16x8 ka1 = *(const bf16x8*)&Ks[(32 + ql) * 64 + ((hi * 8) ^ xs)];
      s0 = __builtin_amdgcn_mfma_f32_32x32x16_bf16(ka0, qf[0], zc, 0, 0, 0);
      s1 = __builtin_amdgcn_mfma_f32_32x32x16_bf16(ka1, qf[0], zc, 0, 0, 0);
    }
#pragma unroll
    for (int s = 1; s < 4; ++s) {
      bf16x8 ka0 = *(const bf16x8*)&Ks[ql * 64 + ((s * 16 + hi * 8) ^ xs)];
      bf16x8 ka1 = *(const bf16x8*)&Ks[(32 + ql) * 64 + ((s * 16 + hi * 8) ^ xs)];
      s0 = __builtin_amdgcn_mfma_f32_32x32x16_bf16(ka0, qf[s], s0, 0, 0, 0);
      s1 = __builtin_amdgcn_mfma_f32_32x32x16_bf16(ka1, qf[s], s1, 0, 0, 0);
    }
    __builtin_amdgcn_s_setprio(0);

#pragma unroll
    for (int r = 0; r < 16; ++r) s0[r] = fast_exp2(s0[r]);
#pragma unroll
    for (int r = 0; r < 16; ++r) s1[r] = fast_exp2(s1[r]);
    lp += tree16(s0) + tree16(s1);

    bf16x8 pb[4];
    pack_pb(s0, s1, pb);

    // drain own V(it) loads (K(it+1) stays in flight), then cross-wave barrier
    if (nl) asm volatile("s_waitcnt vmcnt(2)" ::: "memory");
    else    asm volatile("s_waitcnt vmcnt(0)" ::: "memory");
    asm volatile("s_barrier" ::: "memory");
    __builtin_amdgcn_sched_barrier(0);

    __builtin_amdgcn_s_setprio(1);
#pragma unroll
    for (int ks = 0; ks < 4; ++ks) {
      bf16x8 va0 = *(const bf16x8*)&Vb[ql * 64 + ((ks * 16 + hi * 8) ^ xs)];
      bf16x8 va1 = *(const bf16x8*)&Vb[(32 + ql) * 64 + ((ks * 16 + hi * 8) ^ xs)];
      oA = __builtin_amdgcn_mfma_f32_32x32x16_bf16(va0, pb[ks], oA, 0, 0, 0);
      oB = __builtin_amdgcn_mfma_f32_32x32x16_bf16(va1, pb[ks], oB, 0, 0, 0);
    }
    __builtin_amdgcn_s_setprio(0);

    if (nl) {
      asm volatile("s_waitcnt lgkmcnt(0)" ::: "memory");  // own V reads retired
      asm volatile("s_barrier" ::: "memory");             // all waves done with V(it)
      stageV(kvbase + (it + 1) * 64);                     // refill single V buf
    }
  }

  float l = lp + __shfl_xor(lp, 32);
  unsigned short* orow = Opart + ((size_t)(split * 24 + bh) * SS + q0w + ql) * DKH;
#pragma unroll
  for (int g = 0; g < 4; ++g) {
    int d0 = g * 8 + hi * 4;
    *(unsigned*)&orow[d0]          = cvt_pk_bf16(oA[4 * g + 0], oA[4 * g + 1]);
    *(unsigned*)&orow[d0 + 2]      = cvt_pk_bf16(oA[4 * g + 2], oA[4 * g + 3]);
    *(unsigned*)&orow[32 + d0]     = cvt_pk_bf16(oB[4 * g + 0], oB[4 * g + 1]);
    *(unsigned*)&orow[32 + d0 + 2] = cvt_pk_bf16(oB[4 * g + 2], oB[4 * g + 3]);
  }
  if (hi == 0) Lpart[(size_t)(split * 24 + bh) * SS + q0w + ql] = l;
}

// ---------------------------------------------------------------------------
// Output GEMM with fused combine, T14 issue-early/commit-late (r15, proven).
// ---------------------------------------------------------------------------
__global__ __launch_bounds__(256, 2) void out_gemm(
    const unsigned short* __restrict__ Opart, const float* __restrict__ Lpart,
    const unsigned short* __restrict__ Wt, float* __restrict__ out) {
  __shared__ unsigned short As[2][64 * 64];
  __shared__ unsigned short Bs[2][128 * 64];
  const int tid = threadIdx.x;
  const int lane = tid & 63, wave = tid >> 6;
  const int wm = wave >> 1, wn = wave & 1;
  const int l15 = lane & 15, lhi = lane >> 4;
  const int lrow = lane >> 3;
  const int schunk = (lane & 7) ^ lrow;

  int fid = blockIdx.x + 6 * blockIdx.y;
  int nid = (fid & 7) * 96 + (fid >> 3);
  const int bx = nid % 6, by = nid / 6;
  const int m0 = by * 64, n0 = bx * 128;
  const int bB = m0 >> 12, s0 = m0 & 4095;

  const int arow = tid >> 2;
  const int acn = (tid & 3) * 2;
  const int aw0 = arow * 64 + ((acn ^ (arow & 7)) * 8);
  const int aw1 = arow * 64 + (((acn + 1) ^ (arow & 7)) * 8);
  const size_t PS = (size_t)24 * SS * DKH;
  const size_t LS = (size_t)24 * SS;

  uint4 a0_, a1_, c0_, c1_;
  float la_, lb_;

  auto issueA = [&](int k0) {
    const int h = k0 >> 6;
    const size_t pbase = ((size_t)(bB * NH + h) * SS + s0 + arow) * 64 + acn * 8;
    a0_ = *(const uint4*)(Opart + pbase);
    a1_ = *(const uint4*)(Opart + pbase + 8);
    c0_ = *(const uint4*)(Opart + PS + pbase);
    c1_ = *(const uint4*)(Opart + PS + pbase + 8);
    const size_t lidx = (size_t)(bB * NH + h) * SS + s0 + arow;
    la_ = Lpart[lidx];
    lb_ = Lpart[LS + lidx];
  };
  auto issueB = [&](int k0, int buf) {
#pragma unroll
    for (int i = 0; i < 4; ++i) {
      int r = wave * 32 + i * 8;
      gload16(Wt + (size_t)(n0 + r + lrow) * DM + k0 + schunk * 8, &Bs[buf][r * 64]);
    }
  };
  auto commitA = [&](int buf) {
    float inv = 1.0f / (la_ + lb_);
    union { unsigned u[4]; uint4 v; } o0, o1;
    const unsigned* pa = (const unsigned*)&a0_;
    const unsigned* pc = (const unsigned*)&c0_;
#pragma unroll
    for (int i = 0; i < 4; ++i) o0.u[i] = comb2(pa[i], pc[i], inv);
    pa = (const unsigned*)&a1_;
    pc = (const unsigned*)&c1_;
#pragma unroll
    for (int i = 0; i < 4; ++i) o1.u[i] = comb2(pa[i], pc[i], inv);
    *(uint4*)&As[buf][aw0] = o0.v;
    *(uint4*)&As[buf][aw1] = o1.v;
  };

  f32x4 acc[2][4] = {};
  issueA(0); issueB(0, 0); commitA(0);
  issueA(64); issueB(64, 1); commitA(1);

  for (int t = 0; t < 12; ++t) {
    if (t < 11) asm volatile("s_waitcnt vmcnt(4) lgkmcnt(0)" ::: "memory");
    else        asm volatile("s_waitcnt vmcnt(0) lgkmcnt(0)" ::: "memory");
    asm volatile("s_barrier" ::: "memory");
    const int buf = t & 1;
    bf16x8 af[2][2], bfr[4][2];
#pragma unroll
    for (int m = 0; m < 2; ++m) {
      int row = wm * 32 + m * 16 + l15;
#pragma unroll
      for (int ks = 0; ks < 2; ++ks)
        af[m][ks] = *(const bf16x8*)&As[buf][row * 64 + (((ks * 4 + lhi) ^ (row & 7)) * 8)];
    }
#pragma unroll
    for (int n = 0; n < 4; ++n) {
      int row = wn * 64 + n * 16 + l15;
#pragma unroll
      for (int ks = 0; ks < 2; ++ks)
        bfr[n][ks] = *(const bf16x8*)&Bs[buf][row * 64 + (((ks * 4 + lhi) ^ (row & 7)) * 8)];
    }
    asm volatile("s_waitcnt lgkmcnt(0)" ::: "memory");
    asm volatile("s_barrier" ::: "memory");
    const bool more = (t + 2 < 12);
    if (more) { issueA((t + 2) * 64); issueB((t + 2) * 64, buf); }
    __builtin_amdgcn_s_setprio(1);
#pragma unroll
    for (int ks = 0; ks < 2; ++ks)
#pragma unroll
      for (int m = 0; m < 2; ++m)
#pragma unroll
        for (int n = 0; n < 4; ++n)
          acc[m][n] = __builtin_amdgcn_mfma_f32_16x16x32_bf16(af[m][ks], bfr[n][ks], acc[m][n], 0, 0, 0);
    __builtin_amdgcn_s_setprio(0);
    if (more) commitA(buf);
  }

#pragma unroll
  for (int m = 0; m < 2; ++m)
#pragma unroll
    for (int r = 0; r < 4; ++r) {
      int row = m0 + wm * 32 + m * 16 + lhi * 4 + r;
#pragma unroll
      for (int n = 0; n < 4; ++n) {
        int col = n0 + wn * 64 + n * 16 + l15;
        out[(size_t)row * DM + col] = acc[m][n][r];
      }
    }
}

// ---------------------------------------------------------------------------
extern "C" void kernel_launch(void* const* d_in, const int* in_sizes, int n_in,
                              void* d_out, int out_size, void* d_ws, size_t ws_size,
                              hipStream_t stream) {
  const float* Q  = (const float*)d_in[0];
  const float* K  = (const float*)d_in[1];
  const float* V  = (const float*)d_in[2];
  const float* WQ = (const float*)d_in[3];
  const float* WK = (const float*)d_in[4];
  const float* WV = (const float*)d_in[5];
  const float* WO = (const float*)d_in[6];
  char* ws = (char*)d_ws;

  const size_t WSZ = (size_t)DM * DM * 2;
  const size_t ABF = (size_t)2 * SS * DM * 2;  // 12,582,912 bytes
  unsigned short* w_base  = (unsigned short*)(ws);
  unsigned short* wo_t    = (unsigned short*)(ws + 3 * WSZ);
  unsigned short* qkv_bf  = (unsigned short*)(ws + 4 * WSZ);
  unsigned short* p_base  = (unsigned short*)(ws + 4 * WSZ + 3 * ABF);
  unsigned short* q_p  = p_base;
  unsigned short* k_p  = p_base + ABF / 2;
  unsigned short* v_t  = p_base + ABF;
  unsigned short* opart = qkv_bf;
  float* lpart = (float*)(ws + 4 * WSZ + 2 * ABF);

  prep<<<9216 + 2304, 256, 0, stream>>>(
      Q, K, V, WQ, WK, WV, WO, qkv_bf,
      w_base, w_base + WSZ / 2, w_base + WSZ, wo_t);

  proj_gemm3<<<dim3(8, 64, 3), 256, 0, stream>>>(qkv_bf, w_base, p_base);

  flash_attn<<<dim3(32, 24, 2), 256, 0, stream>>>(q_p, k_p, v_t, opart, lpart);

  out_gemm<<<dim3(6, 128), 256, 0, stream>>>(opart, lpart, wo_t, (float*)d_out);
}

// Round 17
// 251.084 us; speedup vs baseline: 2.7444x; 2.7444x over previous
//
#include <hip/hip_runtime.h>
#include <hip/hip_bf16.h>
#include <stdint.h>
#include <stddef.h>

#define NH 12
#define DKH 64
#define DM 768
#define SS 4096

typedef __attribute__((ext_vector_type(8))) short bf16x8;
typedef __attribute__((ext_vector_type(4))) float f32x4;
typedef __attribute__((ext_vector_type(16))) float f32x16;

__device__ __forceinline__ unsigned short f2bf(float x) {
  union { float f; unsigned int u; } a; a.f = x;
  unsigned int r = a.u + 0x7fffu + ((a.u >> 16) & 1u);
  return (unsigned short)(r >> 16);
}

__device__ __forceinline__ unsigned pkbf2(float a, float b) {
  union { __hip_bfloat162 h; unsigned u; } x;
  x.h = __float22bfloat162_rn(float2{a, b});
  return x.u;
}

__device__ __forceinline__ unsigned cvt_pk_bf16(float lo, float hi) {
  unsigned r;
  asm("v_cvt_pk_bf16_f32 %0, %1, %2" : "=v"(r) : "v"(lo), "v"(hi));
  return r;
}

__device__ __forceinline__ void plane32_swap(unsigned& a, unsigned& b) {
  asm("v_permlane32_swap_b32 %0, %1" : "+v"(a), "+v"(b));
}

__device__ __forceinline__ float fast_exp2(float x) {
#if __has_builtin(__builtin_amdgcn_exp2f)
  return __builtin_amdgcn_exp2f(x);
#else
  return exp2f(x);
#endif
}

// combine two bf16x2 words from the two KV-split partials, scale by inv
__device__ __forceinline__ unsigned comb2(unsigned pa, unsigned pb, float inv) {
  union { unsigned v; float f; } lo0, hi0, lo1, hi1;
  lo0.v = (pa & 0xffffu) << 16; hi0.v = pa & 0xffff0000u;
  lo1.v = (pb & 0xffffu) << 16; hi1.v = pb & 0xffff0000u;
  return pkbf2((lo0.f + lo1.f) * inv, (hi0.f + hi1.f) * inv);
}

// global -> LDS async 16B/lane. LDS dest is wave-uniform base + lane*16.
__device__ __forceinline__ void gload16(const void* g, void* l) {
  __builtin_amdgcn_global_load_lds(
      (const __attribute__((address_space(1))) void*)g,
      (__attribute__((address_space(3))) void*)l, 16, 0, 0);
}

// ---------------------------------------------------------------------------
// Prep: weights only (qkv conversion eliminated — proj reads fp32 directly).
// wq gets Q-scale 0.125*log2e folded in.
// ---------------------------------------------------------------------------
__global__ __launch_bounds__(256) void prep_w(
    const float* __restrict__ WQ, const float* __restrict__ WK,
    const float* __restrict__ WV, const float* __restrict__ WO,
    unsigned short* __restrict__ wq, unsigned short* __restrict__ wk,
    unsigned short* __restrict__ wv, unsigned short* __restrict__ wo) {
  int idx = blockIdx.x * 256 + threadIdx.x;
  if (idx >= DM * DM) return;
  int n = idx / DM, k = idx % DM;
  int src = ((n >> 6) * DM + k) * DKH + (n & 63);
  wq[idx] = f2bf(WQ[src] * 0.18033688011112042f);
  wk[idx] = f2bf(WK[src]);
  wv[idx] = f2bf(WV[src]);
  wo[idx] = f2bf(WO[k * DM + n]);
}

// ---------------------------------------------------------------------------
// Merged projection GEMM, fp32 A read DIRECTLY (T14 issue-early/commit-late:
// 8 float4 loads issued before MFMA block; convert + swizzled ds_write after).
// B via gload16. Per-wave vmem FIFO per tile: A[8] then B[3]; commit's
// implicit wait drains to <=3, so top-of-iter vmcnt(3) has B(t) landed.
// Tile 128(M) x 96(N), BK=64, 4 waves. grid (8,64,3)=1536, XCD-swizzled.
// Uniform swapped MFMA; z==2 transposed store.
// ---------------------------------------------------------------------------
__global__ __launch_bounds__(256, 2) void proj_gemm3(
    const float* __restrict__ Qin, const float* __restrict__ Kin,
    const float* __restrict__ Vin, const unsigned short* __restrict__ Wbase,
    unsigned short* __restrict__ Obase) {
  __shared__ unsigned short As[2][128 * 64];  // 32 KB
  __shared__ unsigned short Bs[2][96 * 64];   // 24 KB
  const int tid = threadIdx.x;
  const int lane = tid & 63, wave = tid >> 6;
  const int wm = wave >> 1, wn = wave & 1;
  const int l15 = lane & 15, lhi = lane >> 4;
  const int lrow = lane >> 3;
  const int schunk = (lane & 7) ^ lrow;

  int fid = blockIdx.x + (blockIdx.y << 3) + (blockIdx.z << 9);
  int nid = (fid & 7) * 192 + (fid >> 3);
  const int bx = nid & 7;
  const int rem = nid >> 3;
  const int by = rem & 63, z = rem >> 6;
  const bool z2 = (z == 2);

  const float* A = (z == 0) ? Qin : (z == 1) ? Kin : Vin;
  const unsigned short* Wt = Wbase + (size_t)z * DM * DM;
  unsigned short* out = Obase + (size_t)z * 2 * NH * SS * DKH;
  const int m0 = by * 128, n0 = bx * 96;

  const int arow = tid >> 1, ahalf = tid & 1;  // 2 threads/row, 32 fp32 each

  // in-flight fp32 A registers (issue -> MFMA -> commit)
  float4 f0_, f1_, f2_, f3_, f4_, f5_, f6_, f7_;

  auto issueA = [&](int k0) {
    const float* ap = A + (size_t)(m0 + arow) * DM + k0 + ahalf * 32;
    f0_ = *(const float4*)(ap + 0);  f1_ = *(const float4*)(ap + 4);
    f2_ = *(const float4*)(ap + 8);  f3_ = *(const float4*)(ap + 12);
    f4_ = *(const float4*)(ap + 16); f5_ = *(const float4*)(ap + 20);
    f6_ = *(const float4*)(ap + 24); f7_ = *(const float4*)(ap + 28);
  };
  auto issueB = [&](int k0, int buf) {
#pragma unroll
    for (int i = 0; i < 3; ++i) {
      int r = wave * 24 + i * 8;
      gload16(Wt + (size_t)(n0 + r + lrow) * DM + k0 + schunk * 8, &Bs[buf][r * 64]);
    }
  };
  auto commitA = [&](int buf) {
    union { unsigned u[4]; uint4 v; } p0, p1, p2, p3;
    p0.u[0] = pkbf2(f0_.x, f0_.y); p0.u[1] = pkbf2(f0_.z, f0_.w);
    p0.u[2] = pkbf2(f1_.x, f1_.y); p0.u[3] = pkbf2(f1_.z, f1_.w);
    p1.u[0] = pkbf2(f2_.x, f2_.y); p1.u[1] = pkbf2(f2_.z, f2_.w);
    p1.u[2] = pkbf2(f3_.x, f3_.y); p1.u[3] = pkbf2(f3_.z, f3_.w);
    p2.u[0] = pkbf2(f4_.x, f4_.y); p2.u[1] = pkbf2(f4_.z, f4_.w);
    p2.u[2] = pkbf2(f5_.x, f5_.y); p2.u[3] = pkbf2(f5_.z, f5_.w);
    p3.u[0] = pkbf2(f6_.x, f6_.y); p3.u[1] = pkbf2(f6_.z, f6_.w);
    p3.u[2] = pkbf2(f7_.x, f7_.y); p3.u[3] = pkbf2(f7_.z, f7_.w);
    const int rs = (arow & 7);
    *(uint4*)&As[buf][arow * 64 + (((ahalf * 4 + 0) ^ rs) * 8)] = p0.v;
    *(uint4*)&As[buf][arow * 64 + (((ahalf * 4 + 1) ^ rs) * 8)] = p1.v;
    *(uint4*)&As[buf][arow * 64 + (((ahalf * 4 + 2) ^ rs) * 8)] = p2.v;
    *(uint4*)&As[buf][arow * 64 + (((ahalf * 4 + 3) ^ rs) * 8)] = p3.v;
  };

  f32x4 acc[4][3] = {};
  issueA(0);  issueB(0, 0);  commitA(0);
  issueA(64); issueB(64, 1); commitA(1);

  for (int t = 0; t < 12; ++t) {
    if (t < 11) asm volatile("s_waitcnt vmcnt(3) lgkmcnt(0)" ::: "memory");
    else        asm volatile("s_waitcnt vmcnt(0) lgkmcnt(0)" ::: "memory");
    asm volatile("s_barrier" ::: "memory");
    const int buf = t & 1;
    bf16x8 af[4][2], bfr[3][2];
#pragma unroll
    for (int m = 0; m < 4; ++m) {
      int row = wm * 64 + m * 16 + l15;
#pragma unroll
      for (int ks = 0; ks < 2; ++ks)
        af[m][ks] = *(const bf16x8*)&As[buf][row * 64 + (((ks * 4 + lhi) ^ (row & 7)) * 8)];
    }
#pragma unroll
    for (int n = 0; n < 3; ++n) {
      int row = wn * 48 + n * 16 + l15;
#pragma unroll
      for (int ks = 0; ks < 2; ++ks)
        bfr[n][ks] = *(const bf16x8*)&Bs[buf][row * 64 + (((ks * 4 + lhi) ^ (row & 7)) * 8)];
    }
    asm volatile("s_waitcnt lgkmcnt(0)" ::: "memory");
    asm volatile("s_barrier" ::: "memory");
    const bool more = (t + 2 < 12);
    if (more) { issueA((t + 2) * 64); issueB((t + 2) * 64, buf); }
    __builtin_amdgcn_s_setprio(1);
#pragma unroll
    for (int ks = 0; ks < 2; ++ks)
#pragma unroll
      for (int m = 0; m < 4; ++m)
#pragma unroll
        for (int n = 0; n < 3; ++n)
          acc[m][n] = __builtin_amdgcn_mfma_f32_16x16x32_bf16(bfr[n][ks], af[m][ks], acc[m][n], 0, 0, 0);
    __builtin_amdgcn_s_setprio(0);
    if (more) commitA(buf);  // implicit vmcnt<=3 lands post-MFMA
  }

  if (!z2) {
#pragma unroll
    for (int m = 0; m < 4; ++m) {
      int srow = m0 + wm * 64 + m * 16 + l15;
      int bb = srow >> 12, s = srow & 4095;
#pragma unroll
      for (int n = 0; n < 3; ++n) {
        int colb = n0 + wn * 48 + n * 16 + lhi * 4;
        int hh = colb >> 6, dk = colb & 63;
        union { unsigned short u[4]; uint2 v; } p;
#pragma unroll
        for (int r = 0; r < 4; ++r) p.u[r] = f2bf(acc[m][n][r]);
        *(uint2*)&out[((size_t)(bb * NH + hh) * SS + s) * DKH + dk] = p.v;
      }
    }
  } else {
#pragma unroll
    for (int m = 0; m < 4; ++m) {
      int srow = m0 + wm * 64 + m * 16 + l15;
      int bb = srow >> 12, s = srow & 4095;
#pragma unroll
      for (int n = 0; n < 3; ++n) {
#pragma unroll
        for (int r = 0; r < 4; ++r) {
          int col = n0 + wn * 48 + n * 16 + lhi * 4 + r;
          int hh = col >> 6, dk = col & 63;
          out[((size_t)(bb * NH + hh) * DKH + dk) * SS + s] = f2bf(acc[m][n][r]);
        }
      }
    }
  }
}

// ---------------------------------------------------------------------------
// pack 32 f32 P-values into 4 PV B-fragments (proven mapping)
// ---------------------------------------------------------------------------
__device__ __forceinline__ void pack_pb(const f32x16& s0, const f32x16& s1, bf16x8* pb) {
#pragma unroll
  for (int h2 = 0; h2 < 2; ++h2) {
    unsigned c0a = cvt_pk_bf16(s0[8 * h2 + 0], s0[8 * h2 + 1]);
    unsigned c1a = cvt_pk_bf16(s0[8 * h2 + 2], s0[8 * h2 + 3]);
    unsigned c0b = cvt_pk_bf16(s0[8 * h2 + 4], s0[8 * h2 + 5]);
    unsigned c1b = cvt_pk_bf16(s0[8 * h2 + 6], s0[8 * h2 + 7]);
    plane32_swap(c0a, c0b);
    plane32_swap(c1a, c1b);
    union { unsigned u[4]; bf16x8 v; } f;
    f.u[0] = c0a; f.u[1] = c1a; f.u[2] = c0b; f.u[3] = c1b;
    pb[h2] = f.v;
  }
#pragma unroll
  for (int h2 = 0; h2 < 2; ++h2) {
    unsigned c0a = cvt_pk_bf16(s1[8 * h2 + 0], s1[8 * h2 + 1]);
    unsigned c1a = cvt_pk_bf16(s1[8 * h2 + 2], s1[8 * h2 + 3]);
    unsigned c0b = cvt_pk_bf16(s1[8 * h2 + 4], s1[8 * h2 + 5]);
    unsigned c1b = cvt_pk_bf16(s1[8 * h2 + 6], s1[8 * h2 + 7]);
    plane32_swap(c0a, c0b);
    plane32_swap(c1a, c1b);
    union { unsigned u[4]; bf16x8 v; } f;
    f.u[0] = c0a; f.u[1] = c1a; f.u[2] = c0b; f.u[3] = c1b;
    pb[2 + h2] = f.v;
  }
}

__device__ __forceinline__ float tree16(const f32x16& v) {
  float a = (v[0] + v[1]) + (v[2] + v[3]);
  float b = (v[4] + v[5]) + (v[6] + v[7]);
  float c = (v[8] + v[9]) + (v[10] + v[11]);
  float d = (v[12] + v[13]) + (v[14] + v[15]);
  return (a + b) + (c + d);
}

// ---------------------------------------------------------------------------
// Flash attention (r15 exact, 120 us proven; (256,4) — REGISTER-BOUND, the
// true footprint is ~124 unified regs incl. AGPRs; never raise min-waves).
// Split-KV x2 across blocks, bf16 partials. 4 waves x 32q, dbuf K+V (32 KB).
// ---------------------------------------------------------------------------
__global__ __launch_bounds__(256, 4) void flash_attn(
    const unsigned short* __restrict__ Qp, const unsigned short* __restrict__ Kp,
    const unsigned short* __restrict__ Vt, unsigned short* __restrict__ Opart,
    float* __restrict__ Lpart) {
  __shared__ unsigned short KV[2][8192];  // [buf][K 64x64 | V^T 64x64] 32 KB
  const int tid = threadIdx.x;
  const int lane = tid & 63, wave = tid >> 6;
  const int ql = lane & 31, hi = lane >> 5;

  int fid = blockIdx.x + (blockIdx.y << 5) + (blockIdx.z << 9) + (blockIdx.z << 8);
  int nid = (fid & 7) * 192 + (fid >> 3);
  const int qb = nid & 31;
  const int rem = nid >> 5;
  const int bh = rem % 24, split = rem / 24;
  const int q0w = qb * 128 + wave * 32;
  const int kvbase = split * (SS / 2);

  bf16x8 qf[4];
  {
    const unsigned short* qp = Qp + ((size_t)bh * SS + q0w + ql) * DKH;
#pragma unroll
    for (int s = 0; s < 4; ++s)
      qf[s] = *(const bf16x8*)(qp + s * 16 + hi * 8);
  }

  const unsigned short* gK = Kp + (size_t)bh * SS * DKH;
  const unsigned short* gV = Vt + (size_t)bh * DKH * SS;
  const int lrow = lane >> 3;
  const int sch = ((lane & 7) ^ lrow) * 8;
  const int xs = (ql & 7) << 3;

  auto stage = [&](int kv0, int buf) {
#pragma unroll
    for (int i = 0; i < 2; ++i) {
      int r = wave * 16 + i * 8;
      gload16(gK + (size_t)(kv0 + r + lrow) * DKH + sch, &KV[buf][r * 64]);
      gload16(gV + (size_t)(r + lrow) * SS + kv0 + sch, &KV[buf][4096 + r * 64]);
    }
  };

  stage(kvbase, 0);

  f32x16 oA = {}, oB = {};
  float lp = 0.f;
  const f32x16 zc = {};

  for (int it = 0; it < 32; ++it) {
    asm volatile("s_waitcnt vmcnt(0)" ::: "memory");
    __builtin_amdgcn_s_barrier();
    __builtin_amdgcn_sched_barrier(0);
    const int buf = it & 1;
    if (it + 1 < 32) stage(kvbase + (it + 1) * 64, buf ^ 1);
    const unsigned short* Ks = &KV[buf][0];
    const unsigned short* Vs = &KV[buf][4096];

    f32x16 s0, s1;
    __builtin_amdgcn_s_setprio(1);
    {
      bf16x8 ka0 = *(const bf16x8*)&Ks[ql * 64 + ((hi * 8) ^ xs)];
      bf16x8 ka1 = *(const bf16x8*)&Ks[(32 + ql) * 64 + ((hi * 8) ^ xs)];
      s0 = __builtin_amdgcn_mfma_f32_32x32x16_bf16(ka0, qf[0], zc, 0, 0, 0);
      s1 = __builtin_amdgcn_mfma_f32_32x32x16_bf16(ka1, qf[0], zc, 0, 0, 0);
    }
#pragma unroll
    for (int s = 1; s < 4; ++s) {
      bf16x8 ka0 = *(const bf16x8*)&Ks[ql * 64 + ((s * 16 + hi * 8) ^ xs)];
      bf16x8 ka1 = *(const bf16x8*)&Ks[(32 + ql) * 64 + ((s * 16 + hi * 8) ^ xs)];
      s0 = __builtin_amdgcn_mfma_f32_32x32x16_bf16(ka0, qf[s], s0, 0, 0, 0);
      s1 = __builtin_amdgcn_mfma_f32_32x32x16_bf16(ka1, qf[s], s1, 0, 0, 0);
    }
    __builtin_amdgcn_s_setprio(0);

#pragma unroll
    for (int r = 0; r < 16; ++r) s0[r] = fast_exp2(s0[r]);
#pragma unroll
    for (int r = 0; r < 16; ++r) s1[r] = fast_exp2(s1[r]);
    lp += tree16(s0) + tree16(s1);

    bf16x8 pb[4];
    pack_pb(s0, s1, pb);

    __builtin_amdgcn_s_setprio(1);
#pragma unroll
    for (int ks = 0; ks < 4; ++ks) {
      bf16x8 va0 = *(const bf16x8*)&Vs[ql * 64 + ((ks * 16 + hi * 8) ^ xs)];
      bf16x8 va1 = *(const bf16x8*)&Vs[(32 + ql) * 64 + ((ks * 16 + hi * 8) ^ xs)];
      oA = __builtin_amdgcn_mfma_f32_32x32x16_bf16(va0, pb[ks], oA, 0, 0, 0);
      oB = __builtin_amdgcn_mfma_f32_32x32x16_bf16(va1, pb[ks], oB, 0, 0, 0);
    }
    __builtin_amdgcn_s_setprio(0);
  }

  float l = lp + __shfl_xor(lp, 32);
  unsigned short* orow = Opart + ((size_t)(split * 24 + bh) * SS + q0w + ql) * DKH;
#pragma unroll
  for (int g = 0; g < 4; ++g) {
    int d0 = g * 8 + hi * 4;
    *(unsigned*)&orow[d0]          = cvt_pk_bf16(oA[4 * g + 0], oA[4 * g + 1]);
    *(unsigned*)&orow[d0 + 2]      = cvt_pk_bf16(oA[4 * g + 2], oA[4 * g + 3]);
    *(unsigned*)&orow[32 + d0]     = cvt_pk_bf16(oB[4 * g + 0], oB[4 * g + 1]);
    *(unsigned*)&orow[32 + d0 + 2] = cvt_pk_bf16(oB[4 * g + 2], oB[4 * g + 3]);
  }
  if (hi == 0) Lpart[(size_t)(split * 24 + bh) * SS + q0w + ql] = l;
}

// ---------------------------------------------------------------------------
// Output GEMM with fused combine, T14 issue-early/commit-late (r15, proven).
// ---------------------------------------------------------------------------
__global__ __launch_bounds__(256, 2) void out_gemm(
    const unsigned short* __restrict__ Opart, const float* __restrict__ Lpart,
    const unsigned short* __restrict__ Wt, float* __restrict__ out) {
  __shared__ unsigned short As[2][64 * 64];
  __shared__ unsigned short Bs[2][128 * 64];
  const int tid = threadIdx.x;
  const int lane = tid & 63, wave = tid >> 6;
  const int wm = wave >> 1, wn = wave & 1;
  const int l15 = lane & 15, lhi = lane >> 4;
  const int lrow = lane >> 3;
  const int schunk = (lane & 7) ^ lrow;

  int fid = blockIdx.x + 6 * blockIdx.y;
  int nid = (fid & 7) * 96 + (fid >> 3);
  const int bx = nid % 6, by = nid / 6;
  const int m0 = by * 64, n0 = bx * 128;
  const int bB = m0 >> 12, s0 = m0 & 4095;

  const int arow = tid >> 2;
  const int acn = (tid & 3) * 2;
  const int aw0 = arow * 64 + ((acn ^ (arow & 7)) * 8);
  const int aw1 = arow * 64 + (((acn + 1) ^ (arow & 7)) * 8);
  const size_t PS = (size_t)24 * SS * DKH;
  const size_t LS = (size_t)24 * SS;

  uint4 a0_, a1_, c0_, c1_;
  float la_, lb_;

  auto issueA = [&](int k0) {
    const int h = k0 >> 6;
    const size_t pbase = ((size_t)(bB * NH + h) * SS + s0 + arow) * 64 + acn * 8;
    a0_ = *(const uint4*)(Opart + pbase);
    a1_ = *(const uint4*)(Opart + pbase + 8);
    c0_ = *(const uint4*)(Opart + PS + pbase);
    c1_ = *(const uint4*)(Opart + PS + pbase + 8);
    const size_t lidx = (size_t)(bB * NH + h) * SS + s0 + arow;
    la_ = Lpart[lidx];
    lb_ = Lpart[LS + lidx];
  };
  auto issueB = [&](int k0, int buf) {
#pragma unroll
    for (int i = 0; i < 4; ++i) {
      int r = wave * 32 + i * 8;
      gload16(Wt + (size_t)(n0 + r + lrow) * DM + k0 + schunk * 8, &Bs[buf][r * 64]);
    }
  };
  auto commitA = [&](int buf) {
    float inv = 1.0f / (la_ + lb_);
    union { unsigned u[4]; uint4 v; } o0, o1;
    const unsigned* pa = (const unsigned*)&a0_;
    const unsigned* pc = (const unsigned*)&c0_;
#pragma unroll
    for (int i = 0; i < 4; ++i) o0.u[i] = comb2(pa[i], pc[i], inv);
    pa = (const unsigned*)&a1_;
    pc = (const unsigned*)&c1_;
#pragma unroll
    for (int i = 0; i < 4; ++i) o1.u[i] = comb2(pa[i], pc[i], inv);
    *(uint4*)&As[buf][aw0] = o0.v;
    *(uint4*)&As[buf][aw1] = o1.v;
  };

  f32x4 acc[2][4] = {};
  issueA(0); issueB(0, 0); commitA(0);
  issueA(64); issueB(64, 1); commitA(1);

  for (int t = 0; t < 12; ++t) {
    if (t < 11) asm volatile("s_waitcnt vmcnt(4) lgkmcnt(0)" ::: "memory");
    else        asm volatile("s_waitcnt vmcnt(0) lgkmcnt(0)" ::: "memory");
    asm volatile("s_barrier" ::: "memory");
    const int buf = t & 1;
    bf16x8 af[2][2], bfr[4][2];
#pragma unroll
    for (int m = 0; m < 2; ++m) {
      int row = wm * 32 + m * 16 + l15;
#pragma unroll
      for (int ks = 0; ks < 2; ++ks)
        af[m][ks] = *(const bf16x8*)&As[buf][row * 64 + (((ks * 4 + lhi) ^ (row & 7)) * 8)];
    }
#pragma unroll
    for (int n = 0; n < 4; ++n) {
      int row = wn * 64 + n * 16 + l15;
#pragma unroll
      for (int ks = 0; ks < 2; ++ks)
        bfr[n][ks] = *(const bf16x8*)&Bs[buf][row * 64 + (((ks * 4 + lhi) ^ (row & 7)) * 8)];
    }
    asm volatile("s_waitcnt lgkmcnt(0)" ::: "memory");
    asm volatile("s_barrier" ::: "memory");
    const bool more = (t + 2 < 12);
    if (more) { issueA((t + 2) * 64); issueB((t + 2) * 64, buf); }
    __builtin_amdgcn_s_setprio(1);
#pragma unroll
    for (int ks = 0; ks < 2; ++ks)
#pragma unroll
      for (int m = 0; m < 2; ++m)
#pragma unroll
        for (int n = 0; n < 4; ++n)
          acc[m][n] = __builtin_amdgcn_mfma_f32_16x16x32_bf16(af[m][ks], bfr[n][ks], acc[m][n], 0, 0, 0);
    __builtin_amdgcn_s_setprio(0);
    if (more) commitA(buf);
  }

#pragma unroll
  for (int m = 0; m < 2; ++m)
#pragma unroll
    for (int r = 0; r < 4; ++r) {
      int row = m0 + wm * 32 + m * 16 + lhi * 4 + r;
#pragma unroll
      for (int n = 0; n < 4; ++n) {
        int col = n0 + wn * 64 + n * 16 + l15;
        out[(size_t)row * DM + col] = acc[m][n][r];
      }
    }
}

// ---------------------------------------------------------------------------
extern "C" void kernel_launch(void* const* d_in, const int* in_sizes, int n_in,
                              void* d_out, int out_size, void* d_ws, size_t ws_size,
                              hipStream_t stream) {
  const float* Q  = (const float*)d_in[0];
  const float* K  = (const float*)d_in[1];
  const float* V  = (const float*)d_in[2];
  const float* WQ = (const float*)d_in[3];
  const float* WK = (const float*)d_in[4];
  const float* WV = (const float*)d_in[5];
  const float* WO = (const float*)d_in[6];
  char* ws = (char*)d_ws;

  const size_t WSZ = (size_t)DM * DM * 2;
  const size_t ABF = (size_t)2 * SS * DM * 2;  // 12,582,912 bytes
  unsigned short* w_base  = (unsigned short*)(ws);
  unsigned short* wo_t    = (unsigned short*)(ws + 3 * WSZ);
  unsigned short* scratch = (unsigned short*)(ws + 4 * WSZ);  // former qkv area
  unsigned short* p_base  = (unsigned short*)(ws + 4 * WSZ + 3 * ABF);
  unsigned short* q_p  = p_base;
  unsigned short* k_p  = p_base + ABF / 2;
  unsigned short* v_t  = p_base + ABF;
  unsigned short* opart = scratch;  // 25.2 MB partials
  float* lpart = (float*)(ws + 4 * WSZ + 2 * ABF);

  prep_w<<<(DM * DM + 255) / 256, 256, 0, stream>>>(
      WQ, WK, WV, WO, w_base, w_base + WSZ / 2, w_base + WSZ, wo_t);

  proj_gemm3<<<dim3(8, 64, 3), 256, 0, stream>>>(Q, K, V, w_base, p_base);

  flash_attn<<<dim3(32, 24, 2), 256, 0, stream>>>(q_p, k_p, v_t, opart, lpart);

  out_gemm<<<dim3(6, 128), 256, 0, stream>>>(opart, lpart, wo_t, (float*)d_out);
}

// Round 18
// 205.047 us; speedup vs baseline: 3.3605x; 1.2245x over previous
//
#include <hip/hip_runtime.h>
#include <hip/hip_bf16.h>
#include <stdint.h>
#include <stddef.h>

#define NH 12
#define DKH 64
#define DM 768
#define SS 4096

typedef __attribute__((ext_vector_type(8))) short bf16x8;
typedef __attribute__((ext_vector_type(4))) float f32x4;
typedef __attribute__((ext_vector_type(16))) float f32x16;

__device__ __forceinline__ unsigned short f2bf(float x) {
  union { float f; unsigned int u; } a; a.f = x;
  unsigned int r = a.u + 0x7fffu + ((a.u >> 16) & 1u);
  return (unsigned short)(r >> 16);
}

__device__ __forceinline__ unsigned pkbf2(float a, float b) {
  union { __hip_bfloat162 h; unsigned u; } x;
  x.h = __float22bfloat162_rn(float2{a, b});
  return x.u;
}

__device__ __forceinline__ unsigned cvt_pk_bf16(float lo, float hi) {
  unsigned r;
  asm("v_cvt_pk_bf16_f32 %0, %1, %2" : "=v"(r) : "v"(lo), "v"(hi));
  return r;
}

__device__ __forceinline__ void plane32_swap(unsigned& a, unsigned& b) {
  asm("v_permlane32_swap_b32 %0, %1" : "+v"(a), "+v"(b));
}

__device__ __forceinline__ float fast_exp2(float x) {
#if __has_builtin(__builtin_amdgcn_exp2f)
  return __builtin_amdgcn_exp2f(x);
#else
  return exp2f(x);
#endif
}

// combine two bf16x2 words from the two KV-split partials, scale by inv
__device__ __forceinline__ unsigned comb2(unsigned pa, unsigned pb, float inv) {
  union { unsigned v; float f; } lo0, hi0, lo1, hi1;
  lo0.v = (pa & 0xffffu) << 16; hi0.v = pa & 0xffff0000u;
  lo1.v = (pb & 0xffffu) << 16; hi1.v = pb & 0xffff0000u;
  return pkbf2((lo0.f + lo1.f) * inv, (hi0.f + hi1.f) * inv);
}

// global -> LDS async 16B/lane. LDS dest is wave-uniform base + lane*16.
__device__ __forceinline__ void gload16(const void* g, void* l) {
  __builtin_amdgcn_global_load_lds(
      (const __attribute__((address_space(1))) void*)g,
      (__attribute__((address_space(3))) void*)l, 16, 0, 0);
}

// ---------------------------------------------------------------------------
// Prep kernel: qkv fp32->bf16 (blocks 0..9215) + weight repack (9216..11519).
// wq gets Q-scale 0.125*log2e folded in.
// ---------------------------------------------------------------------------
__global__ __launch_bounds__(256) void prep(
    const float* __restrict__ Q, const float* __restrict__ K,
    const float* __restrict__ V, const float* __restrict__ WQ,
    const float* __restrict__ WK, const float* __restrict__ WV,
    const float* __restrict__ WO, unsigned short* __restrict__ qkv,
    unsigned short* __restrict__ wq, unsigned short* __restrict__ wk,
    unsigned short* __restrict__ wv, unsigned short* __restrict__ wo) {
  int bx = blockIdx.x;
  if (bx < 9216) {
    int gid = bx * 256 + threadIdx.x;
    int t = gid / 786432, e = gid % 786432;
    const float* src = (t == 0) ? Q : (t == 1) ? K : V;
    float4 a = *(const float4*)(src + (size_t)e * 8);
    float4 c = *(const float4*)(src + (size_t)e * 8 + 4);
    union { unsigned u[4]; uint4 v; } o;
    o.u[0] = pkbf2(a.x, a.y); o.u[1] = pkbf2(a.z, a.w);
    o.u[2] = pkbf2(c.x, c.y); o.u[3] = pkbf2(c.z, c.w);
    *(uint4*)(qkv + (size_t)t * 6291456 + (size_t)e * 8) = o.v;
  } else {
    int idx = (bx - 9216) * 256 + threadIdx.x;
    if (idx >= DM * DM) return;
    int n = idx / DM, k = idx % DM;
    int src = ((n >> 6) * DM + k) * DKH + (n & 63);
    wq[idx] = f2bf(WQ[src] * 0.18033688011112042f);
    wk[idx] = f2bf(WK[src]);
    wv[idx] = f2bf(WV[src]);
    wo[idx] = f2bf(WO[k * DM + n]);
  }
}

// ---------------------------------------------------------------------------
// Merged projection GEMM. UNIFORM swapped MFMA (A-op = W rows, B-op = input
// rows) for all z -> D-row = W-row (dk), D-col = s. z<2 epilogue emits
// 12x 8B stores; z==2 transposed store. bf16 gload_lds dbuf staging.
// ---------------------------------------------------------------------------
__global__ __launch_bounds__(256, 2) void proj_gemm3(
    const unsigned short* __restrict__ Abase,
    const unsigned short* __restrict__ Wbase,
    unsigned short* __restrict__ Obase) {
  __shared__ unsigned short As[2][128 * 64];
  __shared__ unsigned short Bs[2][96 * 64];
  const int tid = threadIdx.x;
  const int lane = tid & 63, wave = tid >> 6;
  const int wm = wave >> 1, wn = wave & 1;
  const int l15 = lane & 15, lhi = lane >> 4;
  const int lrow = lane >> 3;
  const int schunk = (lane & 7) ^ lrow;

  int fid = blockIdx.x + (blockIdx.y << 3) + (blockIdx.z << 9);
  int nid = (fid & 7) * 192 + (fid >> 3);
  const int bx = nid & 7;
  const int rem = nid >> 3;
  const int by = rem & 63, z = rem >> 6;
  const bool z2 = (z == 2);

  const unsigned short* A = Abase + (size_t)z * 6291456;
  const unsigned short* Wt = Wbase + (size_t)z * DM * DM;
  unsigned short* out = Obase + (size_t)z * 2 * NH * SS * DKH;
  const int m0 = by * 128, n0 = bx * 96;

  auto stage = [&](int k0, int buf) {
#pragma unroll
    for (int i = 0; i < 4; ++i) {
      int r = wave * 32 + i * 8;
      gload16(A + (size_t)(m0 + r + lrow) * DM + k0 + schunk * 8, &As[buf][r * 64]);
    }
#pragma unroll
    for (int i = 0; i < 3; ++i) {
      int r = wave * 24 + i * 8;
      gload16(Wt + (size_t)(n0 + r + lrow) * DM + k0 + schunk * 8, &Bs[buf][r * 64]);
    }
  };

  f32x4 acc[4][3] = {};

  stage(0, 0);
  stage(64, 1);

  for (int t = 0; t < 12; ++t) {
    if (t < 11) asm volatile("s_waitcnt vmcnt(7)" ::: "memory");
    else        asm volatile("s_waitcnt vmcnt(0)" ::: "memory");
    asm volatile("s_barrier" ::: "memory");
    const int buf = t & 1;
    bf16x8 af[4][2], bfr[3][2];
#pragma unroll
    for (int m = 0; m < 4; ++m) {
      int row = wm * 64 + m * 16 + l15;
#pragma unroll
      for (int ks = 0; ks < 2; ++ks)
        af[m][ks] = *(const bf16x8*)&As[buf][row * 64 + (((ks * 4 + lhi) ^ (row & 7)) * 8)];
    }
#pragma unroll
    for (int n = 0; n < 3; ++n) {
      int row = wn * 48 + n * 16 + l15;
#pragma unroll
      for (int ks = 0; ks < 2; ++ks)
        bfr[n][ks] = *(const bf16x8*)&Bs[buf][row * 64 + (((ks * 4 + lhi) ^ (row & 7)) * 8)];
    }
    asm volatile("s_waitcnt lgkmcnt(0)" ::: "memory");
    asm volatile("s_barrier" ::: "memory");
    if (t + 2 < 12) stage((t + 2) * 64, buf);
    __builtin_amdgcn_s_setprio(1);
#pragma unroll
    for (int ks = 0; ks < 2; ++ks)
#pragma unroll
      for (int m = 0; m < 4; ++m)
#pragma unroll
        for (int n = 0; n < 3; ++n)
          acc[m][n] = __builtin_amdgcn_mfma_f32_16x16x32_bf16(bfr[n][ks], af[m][ks], acc[m][n], 0, 0, 0);
    __builtin_amdgcn_s_setprio(0);
  }

  // D-row = W-row (dk dim, indexed by lhi*4+r within tile-col), D-col = s (l15)
  if (!z2) {
#pragma unroll
    for (int m = 0; m < 4; ++m) {
      int srow = m0 + wm * 64 + m * 16 + l15;
      int bb = srow >> 12, s = srow & 4095;
#pragma unroll
      for (int n = 0; n < 3; ++n) {
        int colb = n0 + wn * 48 + n * 16 + lhi * 4;  // 4-aligned, run stays in head
        int hh = colb >> 6, dk = colb & 63;
        union { unsigned short u[4]; uint2 v; } p;
#pragma unroll
        for (int r = 0; r < 4; ++r) p.u[r] = f2bf(acc[m][n][r]);
        *(uint2*)&out[((size_t)(bb * NH + hh) * SS + s) * DKH + dk] = p.v;
      }
    }
  } else {
#pragma unroll
    for (int m = 0; m < 4; ++m) {
      int srow = m0 + wm * 64 + m * 16 + l15;
      int bb = srow >> 12, s = srow & 4095;
#pragma unroll
      for (int n = 0; n < 3; ++n) {
#pragma unroll
        for (int r = 0; r < 4; ++r) {
          int col = n0 + wn * 48 + n * 16 + lhi * 4 + r;
          int hh = col >> 6, dk = col & 63;
          out[((size_t)(bb * NH + hh) * DKH + dk) * SS + s] = f2bf(acc[m][n][r]);
        }
      }
    }
  }
}

// ---------------------------------------------------------------------------
// pack 32 f32 P-values into 4 PV B-fragments (proven mapping)
// ---------------------------------------------------------------------------
__device__ __forceinline__ void pack_pb(const f32x16& s0, const f32x16& s1, bf16x8* pb) {
#pragma unroll
  for (int h2 = 0; h2 < 2; ++h2) {
    unsigned c0a = cvt_pk_bf16(s0[8 * h2 + 0], s0[8 * h2 + 1]);
    unsigned c1a = cvt_pk_bf16(s0[8 * h2 + 2], s0[8 * h2 + 3]);
    unsigned c0b = cvt_pk_bf16(s0[8 * h2 + 4], s0[8 * h2 + 5]);
    unsigned c1b = cvt_pk_bf16(s0[8 * h2 + 6], s0[8 * h2 + 7]);
    plane32_swap(c0a, c0b);
    plane32_swap(c1a, c1b);
    union { unsigned u[4]; bf16x8 v; } f;
    f.u[0] = c0a; f.u[1] = c1a; f.u[2] = c0b; f.u[3] = c1b;
    pb[h2] = f.v;
  }
#pragma unroll
  for (int h2 = 0; h2 < 2; ++h2) {
    unsigned c0a = cvt_pk_bf16(s1[8 * h2 + 0], s1[8 * h2 + 1]);
    unsigned c1a = cvt_pk_bf16(s1[8 * h2 + 2], s1[8 * h2 + 3]);
    unsigned c0b = cvt_pk_bf16(s1[8 * h2 + 4], s1[8 * h2 + 5]);
    unsigned c1b = cvt_pk_bf16(s1[8 * h2 + 6], s1[8 * h2 + 7]);
    plane32_swap(c0a, c0b);
    plane32_swap(c1a, c1b);
    union { unsigned u[4]; bf16x8 v; } f;
    f.u[0] = c0a; f.u[1] = c1a; f.u[2] = c0b; f.u[3] = c1b;
    pb[2 + h2] = f.v;
  }
}

__device__ __forceinline__ float tree16(const f32x16& v) {
  float a = (v[0] + v[1]) + (v[2] + v[3]);
  float b = (v[4] + v[5]) + (v[6] + v[7]);
  float c = (v[8] + v[9]) + (v[10] + v[11]);
  float d = (v[12] + v[13]) + (v[14] + v[15]);
  return (a + b) + (c + d);
}

// ---------------------------------------------------------------------------
// Flash attention (r12 body, proven 119.6 us): split-KV x2 across blocks,
// bf16 partials. Block = 4 waves x 32q = 128q, dbuf K+V tile (32 KB).
// (256,4) — register-bound (~124 unified regs incl. AGPR); never raise.
// ---------------------------------------------------------------------------
__global__ __launch_bounds__(256, 4) void flash_attn(
    const unsigned short* __restrict__ Qp, const unsigned short* __restrict__ Kp,
    const unsigned short* __restrict__ Vt, unsigned short* __restrict__ Opart,
    float* __restrict__ Lpart) {
  __shared__ unsigned short KV[2][8192];  // [buf][K 64x64 | V^T 64x64] 32 KB
  const int tid = threadIdx.x;
  const int lane = tid & 63, wave = tid >> 6;
  const int ql = lane & 31, hi = lane >> 5;

  int fid = blockIdx.x + (blockIdx.y << 5) + (blockIdx.z << 9) + (blockIdx.z << 8);
  int nid = (fid & 7) * 192 + (fid >> 3);
  const int qb = nid & 31;
  const int rem = nid >> 5;
  const int bh = rem % 24, split = rem / 24;
  const int q0w = qb * 128 + wave * 32;
  const int kvbase = split * (SS / 2);

  bf16x8 qf[4];
  {
    const unsigned short* qp = Qp + ((size_t)bh * SS + q0w + ql) * DKH;
#pragma unroll
    for (int s = 0; s < 4; ++s)
      qf[s] = *(const bf16x8*)(qp + s * 16 + hi * 8);
  }

  const unsigned short* gK = Kp + (size_t)bh * SS * DKH;
  const unsigned short* gV = Vt + (size_t)bh * DKH * SS;
  const int lrow = lane >> 3;
  const int sch = ((lane & 7) ^ lrow) * 8;
  const int xs = (ql & 7) << 3;

  auto stage = [&](int kv0, int buf) {
#pragma unroll
    for (int i = 0; i < 2; ++i) {
      int r = wave * 16 + i * 8;
      gload16(gK + (size_t)(kv0 + r + lrow) * DKH + sch, &KV[buf][r * 64]);
      gload16(gV + (size_t)(r + lrow) * SS + kv0 + sch, &KV[buf][4096 + r * 64]);
    }
  };

  stage(kvbase, 0);

  f32x16 oA = {}, oB = {};
  float lp = 0.f;
  const f32x16 zc = {};

  for (int it = 0; it < 32; ++it) {
    asm volatile("s_waitcnt vmcnt(0)" ::: "memory");
    __builtin_amdgcn_s_barrier();
    __builtin_amdgcn_sched_barrier(0);
    const int buf = it & 1;
    if (it + 1 < 32) stage(kvbase + (it + 1) * 64, buf ^ 1);
    const unsigned short* Ks = &KV[buf][0];
    const unsigned short* Vs = &KV[buf][4096];

    f32x16 s0, s1;
    __builtin_amdgcn_s_setprio(1);
    {
      bf16x8 ka0 = *(const bf16x8*)&Ks[ql * 64 + ((hi * 8) ^ xs)];
      bf16x8 ka1 = *(const bf16x8*)&Ks[(32 + ql) * 64 + ((hi * 8) ^ xs)];
      s0 = __builtin_amdgcn_mfma_f32_32x32x16_bf16(ka0, qf[0], zc, 0, 0, 0);
      s1 = __builtin_amdgcn_mfma_f32_32x32x16_bf16(ka1, qf[0], zc, 0, 0, 0);
    }
#pragma unroll
    for (int s = 1; s < 4; ++s) {
      bf16x8 ka0 = *(const bf16x8*)&Ks[ql * 64 + ((s * 16 + hi * 8) ^ xs)];
      bf16x8 ka1 = *(const bf16x8*)&Ks[(32 + ql) * 64 + ((s * 16 + hi * 8) ^ xs)];
      s0 = __builtin_amdgcn_mfma_f32_32x32x16_bf16(ka0, qf[s], s0, 0, 0, 0);
      s1 = __builtin_amdgcn_mfma_f32_32x32x16_bf16(ka1, qf[s], s1, 0, 0, 0);
    }
    __builtin_amdgcn_s_setprio(0);

#pragma unroll
    for (int r = 0; r < 16; ++r) s0[r] = fast_exp2(s0[r]);
#pragma unroll
    for (int r = 0; r < 16; ++r) s1[r] = fast_exp2(s1[r]);
    lp += tree16(s0) + tree16(s1);

    bf16x8 pb[4];
    pack_pb(s0, s1, pb);

    __builtin_amdgcn_s_setprio(1);
#pragma unroll
    for (int ks = 0; ks < 4; ++ks) {
      bf16x8 va0 = *(const bf16x8*)&Vs[ql * 64 + ((ks * 16 + hi * 8) ^ xs)];
      bf16x8 va1 = *(const bf16x8*)&Vs[(32 + ql) * 64 + ((ks * 16 + hi * 8) ^ xs)];
      oA = __builtin_amdgcn_mfma_f32_32x32x16_bf16(va0, pb[ks], oA, 0, 0, 0);
      oB = __builtin_amdgcn_mfma_f32_32x32x16_bf16(va1, pb[ks], oB, 0, 0, 0);
    }
    __builtin_amdgcn_s_setprio(0);
  }

  float l = lp + __shfl_xor(lp, 32);
  unsigned short* orow = Opart + ((size_t)(split * 24 + bh) * SS + q0w + ql) * DKH;
#pragma unroll
  for (int g = 0; g < 4; ++g) {
    int d0 = g * 8 + hi * 4;
    *(unsigned*)&orow[d0]          = cvt_pk_bf16(oA[4 * g + 0], oA[4 * g + 1]);
    *(unsigned*)&orow[d0 + 2]      = cvt_pk_bf16(oA[4 * g + 2], oA[4 * g + 3]);
    *(unsigned*)&orow[32 + d0]     = cvt_pk_bf16(oB[4 * g + 0], oB[4 * g + 1]);
    *(unsigned*)&orow[32 + d0 + 2] = cvt_pk_bf16(oB[4 * g + 2], oB[4 * g + 3]);
  }
  if (hi == 0) Lpart[(size_t)(split * 24 + bh) * SS + q0w + ql] = l;
}

// ---------------------------------------------------------------------------
// Output GEMM with fused combine, T14 issue-early/commit-late (proven).
// ---------------------------------------------------------------------------
__global__ __launch_bounds__(256, 2) void out_gemm(
    const unsigned short* __restrict__ Opart, const float* __restrict__ Lpart,
    const unsigned short* __restrict__ Wt, float* __restrict__ out) {
  __shared__ unsigned short As[2][64 * 64];
  __shared__ unsigned short Bs[2][128 * 64];
  const int tid = threadIdx.x;
  const int lane = tid & 63, wave = tid >> 6;
  const int wm = wave >> 1, wn = wave & 1;
  const int l15 = lane & 15, lhi = lane >> 4;
  const int lrow = lane >> 3;
  const int schunk = (lane & 7) ^ lrow;

  int fid = blockIdx.x + 6 * blockIdx.y;
  int nid = (fid & 7) * 96 + (fid >> 3);
  const int bx = nid % 6, by = nid / 6;
  const int m0 = by * 64, n0 = bx * 128;
  const int bB = m0 >> 12, s0 = m0 & 4095;

  const int arow = tid >> 2;
  const int acn = (tid & 3) * 2;
  const int aw0 = arow * 64 + ((acn ^ (arow & 7)) * 8);
  const int aw1 = arow * 64 + (((acn + 1) ^ (arow & 7)) * 8);
  const size_t PS = (size_t)24 * SS * DKH;
  const size_t LS = (size_t)24 * SS;

  uint4 a0_, a1_, c0_, c1_;
  float la_, lb_;

  auto issueA = [&](int k0) {
    const int h = k0 >> 6;
    const size_t pbase = ((size_t)(bB * NH + h) * SS + s0 + arow) * 64 + acn * 8;
    a0_ = *(const uint4*)(Opart + pbase);
    a1_ = *(const uint4*)(Opart + pbase + 8);
    c0_ = *(const uint4*)(Opart + PS + pbase);
    c1_ = *(const uint4*)(Opart + PS + pbase + 8);
    const size_t lidx = (size_t)(bB * NH + h) * SS + s0 + arow;
    la_ = Lpart[lidx];
    lb_ = Lpart[LS + lidx];
  };
  auto issueB = [&](int k0, int buf) {
#pragma unroll
    for (int i = 0; i < 4; ++i) {
      int r = wave * 32 + i * 8;
      gload16(Wt + (size_t)(n0 + r + lrow) * DM + k0 + schunk * 8, &Bs[buf][r * 64]);
    }
  };
  auto commitA = [&](int buf) {
    float inv = 1.0f / (la_ + lb_);
    union { unsigned u[4]; uint4 v; } o0, o1;
    const unsigned* pa = (const unsigned*)&a0_;
    const unsigned* pc = (const unsigned*)&c0_;
#pragma unroll
    for (int i = 0; i < 4; ++i) o0.u[i] = comb2(pa[i], pc[i], inv);
    pa = (const unsigned*)&a1_;
    pc = (const unsigned*)&c1_;
#pragma unroll
    for (int i = 0; i < 4; ++i) o1.u[i] = comb2(pa[i], pc[i], inv);
    *(uint4*)&As[buf][aw0] = o0.v;
    *(uint4*)&As[buf][aw1] = o1.v;
  };

  f32x4 acc[2][4] = {};
  issueA(0); issueB(0, 0); commitA(0);
  issueA(64); issueB(64, 1); commitA(1);

  for (int t = 0; t < 12; ++t) {
    if (t < 11) asm volatile("s_waitcnt vmcnt(4) lgkmcnt(0)" ::: "memory");
    else        asm volatile("s_waitcnt vmcnt(0) lgkmcnt(0)" ::: "memory");
    asm volatile("s_barrier" ::: "memory");
    const int buf = t & 1;
    bf16x8 af[2][2], bfr[4][2];
#pragma unroll
    for (int m = 0; m < 2; ++m) {
      int row = wm * 32 + m * 16 + l15;
#pragma unroll
      for (int ks = 0; ks < 2; ++ks)
        af[m][ks] = *(const bf16x8*)&As[buf][row * 64 + (((ks * 4 + lhi) ^ (row & 7)) * 8)];
    }
#pragma unroll
    for (int n = 0; n < 4; ++n) {
      int row = wn * 64 + n * 16 + l15;
#pragma unroll
      for (int ks = 0; ks < 2; ++ks)
        bfr[n][ks] = *(const bf16x8*)&Bs[buf][row * 64 + (((ks * 4 + lhi) ^ (row & 7)) * 8)];
    }
    asm volatile("s_waitcnt lgkmcnt(0)" ::: "memory");
    asm volatile("s_barrier" ::: "memory");
    const bool more = (t + 2 < 12);
    if (more) { issueA((t + 2) * 64); issueB((t + 2) * 64, buf); }
    __builtin_amdgcn_s_setprio(1);
#pragma unroll
    for (int ks = 0; ks < 2; ++ks)
#pragma unroll
      for (int m = 0; m < 2; ++m)
#pragma unroll
        for (int n = 0; n < 4; ++n)
          acc[m][n] = __builtin_amdgcn_mfma_f32_16x16x32_bf16(af[m][ks], bfr[n][ks], acc[m][n], 0, 0, 0);
    __builtin_amdgcn_s_setprio(0);
    if (more) commitA(buf);
  }

#pragma unroll
  for (int m = 0; m < 2; ++m)
#pragma unroll
    for (int r = 0; r < 4; ++r) {
      int row = m0 + wm * 32 + m * 16 + lhi * 4 + r;
#pragma unroll
      for (int n = 0; n < 4; ++n) {
        int col = n0 + wn * 64 + n * 16 + l15;
        out[(size_t)row * DM + col] = acc[m][n][r];
      }
    }
}

// ---------------------------------------------------------------------------
extern "C" void kernel_launch(void* const* d_in, const int* in_sizes, int n_in,
                              void* d_out, int out_size, void* d_ws, size_t ws_size,
                              hipStream_t stream) {
  const float* Q  = (const float*)d_in[0];
  const float* K  = (const float*)d_in[1];
  const float* V  = (const float*)d_in[2];
  const float* WQ = (const float*)d_in[3];
  const float* WK = (const float*)d_in[4];
  const float* WV = (const float*)d_in[5];
  const float* WO = (const float*)d_in[6];
  char* ws = (char*)d_ws;

  const size_t WSZ = (size_t)DM * DM * 2;
  const size_t ABF = (size_t)2 * SS * DM * 2;  // 12,582,912 bytes
  unsigned short* w_base  = (unsigned short*)(ws);
  unsigned short* wo_t    = (unsigned short*)(ws + 3 * WSZ);
  unsigned short* qkv_bf  = (unsigned short*)(ws + 4 * WSZ);
  unsigned short* p_base  = (unsigned short*)(ws + 4 * WSZ + 3 * ABF);
  unsigned short* q_p  = p_base;
  unsigned short* k_p  = p_base + ABF / 2;
  unsigned short* v_t  = p_base + ABF;
  // partials alias the dead qkv_bf region (25.2 MB + 1.6 MB <= 37.7 MB)
  unsigned short* opart = qkv_bf;
  float* lpart = (float*)(ws + 4 * WSZ + 2 * ABF);

  prep<<<9216 + 2304, 256, 0, stream>>>(
      Q, K, V, WQ, WK, WV, WO, qkv_bf,
      w_base, w_base + WSZ / 2, w_base + WSZ, wo_t);

  proj_gemm3<<<dim3(8, 64, 3), 256, 0, stream>>>(qkv_bf, w_base, p_base);

  flash_attn<<<dim3(32, 24, 2), 256, 0, stream>>>(q_p, k_p, v_t, opart, lpart);

  out_gemm<<<dim3(6, 128), 256, 0, stream>>>(opart, lpart, wo_t, (float*)d_out);
}